// Round 3
// baseline (286.357 us; speedup 1.0000x reference)
//
#include <hip/hip_runtime.h>
#include <stdint.h>

#define M_DIM 4096
#define K_DIM 256

typedef unsigned short us;
typedef __attribute__((ext_vector_type(8))) short bf16x8;
typedef __attribute__((ext_vector_type(4))) float f32x4;

static __device__ __forceinline__ float bf2f(unsigned int u){
  unsigned int x = u << 16; float f;
  __builtin_memcpy(&f, &x, 4); return f;
}
static __device__ __forceinline__ us f2bf(float f){
  unsigned int x; __builtin_memcpy(&x, &f, 4);
  unsigned int r = x + 0x7fffu + ((x >> 16) & 1u);
  return (us)(r >> 16);
}

// ---- transpose+cast: [b,256,4096] f32 -> [b,4096,256] bf16, both fmaps one launch --
__global__ void k_transpose_cast(const float* __restrict__ f1,
                                 const float* __restrict__ f2,
                                 us* __restrict__ A, us* __restrict__ B0){
  __shared__ float lds[64][65];
  int z = blockIdx.z;           // 0..3 : b = z&1, which = z>>1
  int b = z & 1, which = z >> 1;
  const float* in = which ? f2 : f1;
  us* out = which ? B0 : A;
  float scale = which ? 1.0f : 0.0625f;   // fold 1/sqrt(256) into A
  int c0 = blockIdx.y * 64, m0 = blockIdx.x * 64;
  const float* ib = in + (size_t)b * K_DIM * M_DIM;
  us* ob = out + (size_t)b * M_DIM * K_DIM;
  int t = threadIdx.x, r = t >> 6, j = t & 63;
#pragma unroll
  for (int k = 0; k < 16; k++)
    lds[r + k*4][j] = ib[(size_t)(c0 + r + k*4) * M_DIM + m0 + j];
  __syncthreads();
#pragma unroll
  for (int k = 0; k < 16; k++)
    ob[(size_t)(m0 + r + k*4) * K_DIM + c0 + j] = f2bf(lds[j][r + k*4] * scale);
}

// ---- pools: B1 (2x2), B2 (4x4), B3 (8x8) all directly from B0, one launch ----------
__global__ void k_pool_all(const us* __restrict__ B0, us* __restrict__ B1,
                           us* __restrict__ B2, us* __restrict__ B3){
  int bid = blockIdx.x;
  us* dst; int wd, f;
  if (bid < 512)      { dst = B1; wd = 32; f = 2; }
  else if (bid < 640) { bid -= 512; dst = B2; wd = 16; f = 4; }
  else                { bid -= 640; dst = B3; wd = 8;  f = 8; }
  int t = threadIdx.x;
  int idx = bid * 4 + (t >> 6);
  int l = t & 63;
  int per = wd * wd;
  int b = idx / per, rem = idx - b * per;
  int y = rem / wd, x = rem - y * wd;
  const us* sb = B0 + (size_t)b * 4096 * K_DIM;
  float s0 = 0, s1 = 0, s2 = 0, s3 = 0;
  for (int dy = 0; dy < f; dy++)
    for (int dx = 0; dx < f; dx++){
      size_t off = ((size_t)(f*y + dy) * 64 + (f*x + dx)) * K_DIM + l * 4;
      uint2 v = *(const uint2*)(sb + off);
      s0 += bf2f(v.x & 0xffff); s1 += bf2f(v.x >> 16);
      s2 += bf2f(v.y & 0xffff); s3 += bf2f(v.y >> 16);
    }
  float inv = 1.0f / (float)(f * f);
  uint2 o;
  o.x = (unsigned)f2bf(s0*inv) | ((unsigned)f2bf(s1*inv) << 16);
  o.y = (unsigned)f2bf(s2*inv) | ((unsigned)f2bf(s3*inv) << 16);
  us* db = dst + (size_t)b * per * K_DIM;
  *(uint2*)(db + (size_t)rem * K_DIM + l * 4) = o;
}

// ---- fused corr+sample: one wave per (pixel, level) --------------------------------
// Taps = dot(f1^T[m], B_lvl[row]) computed 16-at-a-time via MFMA (B-operand = f1
// replicated across the 16 N-columns; A-operand = gathered tap rows). Bilinear
// combine done in-wave from a 112-float LDS slice.
__global__ __launch_bounds__(256) void k_corrsample(
    const us* __restrict__ A,
    const us* __restrict__ B0, const us* __restrict__ B1,
    const us* __restrict__ B2, const us* __restrict__ B3,
    const float* __restrict__ cc, float* __restrict__ out){
  __shared__ float tlds[4][112];
  int wv = threadIdx.x >> 6, lane = threadIdx.x & 63;
  int px = blockIdx.x;          // 0..8191
  int lvl = wv;                 // 4 waves = 4 levels of the same pixel
  int b = px >> 12, m = px & 4095;
  int i = m >> 6, j = m & 63;

  const us* Bl; int wl;
  if (lvl == 0)      { Bl = B0 + (size_t)b * 4096 * K_DIM; wl = 64; }
  else if (lvl == 1) { Bl = B1 + (size_t)b * 1024 * K_DIM; wl = 32; }
  else if (lvl == 2) { Bl = B2 + (size_t)b * 256  * K_DIM; wl = 16; }
  else               { Bl = B3 + (size_t)b * 64   * K_DIM; wl = 8;  }
  float inv = (lvl == 0) ? 1.0f : (lvl == 1) ? 0.5f : (lvl == 2) ? 0.25f : 0.125f;

  float cx = cc[((size_t)(b*2 + 0) * 64 + i) * 64 + j];
  float cy = cc[((size_t)(b*2 + 1) * 64 + i) * 64 + j];
  float xs = cx * inv, ys = cy * inv;
  float x0f = floorf(xs), y0f = floorf(ys);
  int bx0 = (int)x0f - 4, by0 = (int)y0f - 4;
  float fx = xs - x0f, fy = ys - y0f;

  // preload f1 fragments (uniform across lane&15; k-slice by lane>>4), reused 7x
  const us* f1p = A + (size_t)px * K_DIM;
  int ko = (lane >> 4) * 8;
  bf16x8 fB[8];
#pragma unroll
  for (int kk = 0; kk < 8; kk++)
    fB[kk] = *(const bf16x8*)(f1p + kk*32 + ko);

  // 7 groups of 16 taps (100 real + 12 pad)
#pragma unroll
  for (int g = 0; g < 7; g++){
    int tt = g*16 + (lane & 15);
    int vv = (tt * 205) >> 11;           // tt/10 for tt<112
    int uu = tt - vv * 10;
    int ry = by0 + vv, rx = bx0 + uu;
    int ryc = ry < 0 ? 0 : (ry > wl-1 ? wl-1 : ry);
    int rxc = rx < 0 ? 0 : (rx > wl-1 ? wl-1 : rx);
    const us* rowp = Bl + (size_t)(ryc * wl + rxc) * K_DIM;
    f32x4 acc = (f32x4){0.f, 0.f, 0.f, 0.f};
#pragma unroll
    for (int kk = 0; kk < 8; kk++){
      bf16x8 fA = *(const bf16x8*)(rowp + kk*32 + ko);
      acc = __builtin_amdgcn_mfma_f32_16x16x32_bf16(fA, fB[kk], acc, 0, 0, 0);
    }
    // extract: D row r=(lane>>4)*4+reg holds tap g*16+r (any col; use col lane&15==0)
    int rbase = (lane >> 4) * 4;
    float vals[4];
#pragma unroll
    for (int rr = 0; rr < 4; rr++){
      int tr = g*16 + rbase + rr;
      int vr = (tr * 205) >> 11;
      int ur = tr - vr * 10;
      int ryr = by0 + vr, rxr = bx0 + ur;
      bool ok = ((unsigned)ryr < (unsigned)wl) && ((unsigned)rxr < (unsigned)wl)
                && (tr < 100);
      vals[rr] = ok ? acc[rr] : 0.0f;
    }
    if ((lane & 15) == 0){
      float4 v4; v4.x = vals[0]; v4.y = vals[1]; v4.z = vals[2]; v4.w = vals[3];
      *(float4*)&tlds[wv][g*16 + rbase] = v4;
    }
  }

  // in-wave bilinear combine (same-wave LDS RAW; compiler inserts lgkmcnt waits)
  float wx1 = fx, wx0 = 1.0f - fx, wy1 = fy, wy0 = 1.0f - fy;
#pragma unroll
  for (int rep = 0; rep < 2; rep++){
    int o = lane + rep * 64;
    if (o < 81){
      int a = o / 9, d = o - a * 9;     // feature o = a*9 + d ; a=x-offset, d=y-offset
      int t0 = d * 10 + a;
      float s = wy0 * (wx0 * tlds[wv][t0]      + wx1 * tlds[wv][t0 + 1])
              + wy1 * (wx0 * tlds[wv][t0 + 10] + wx1 * tlds[wv][t0 + 11]);
      out[(((size_t)b * 324 + lvl * 81 + o) * 64 + i) * 64 + j] = s;
    }
  }
}

extern "C" void kernel_launch(void* const* d_in, const int* in_sizes, int n_in,
                              void* d_out, int out_size, void* d_ws, size_t ws_size,
                              hipStream_t stream){
  (void)in_sizes; (void)n_in; (void)out_size; (void)ws_size;
  const float* f1 = (const float*)d_in[0];
  const float* f2 = (const float*)d_in[1];
  const float* cc = (const float*)d_in[2];
  float* out = (float*)d_out;
  char* ws = (char*)d_ws;
  us* A  = (us*)(ws + 0);          //  4 MB  f1^T bf16 (scaled 1/16)
  us* B0 = (us*)(ws + 4194304);    //  4 MB  f2^T bf16
  us* B1 = (us*)(ws + 8388608);    //  1 MB
  us* B2 = (us*)(ws + 9437184);    //  256 KB
  us* B3 = (us*)(ws + 9699328);    //  64 KB   (total ~9.5 MB)

  k_transpose_cast<<<dim3(64, 4, 4), dim3(256), 0, stream>>>(f1, f2, A, B0);
  k_pool_all<<<dim3(672), dim3(256), 0, stream>>>(B0, B1, B2, B3);
  k_corrsample<<<dim3(8192), dim3(256), 0, stream>>>(A, B0, B1, B2, B3, cc, out);
}

// Round 4
// 149.823 us; speedup vs baseline: 1.9113x; 1.9113x over previous
//
#include <hip/hip_runtime.h>
#include <stdint.h>

#define M_DIM 4096
#define K_DIM 256

typedef unsigned short us;
typedef __attribute__((ext_vector_type(8))) short bf16x8;
typedef __attribute__((ext_vector_type(4))) float f32x4;

static __device__ __forceinline__ float bf2f(unsigned int u){
  unsigned int x = u << 16; float f;
  __builtin_memcpy(&f, &x, 4); return f;
}
static __device__ __forceinline__ us f2bf(float f){
  unsigned int x; __builtin_memcpy(&x, &f, 4);
  unsigned int r = x + 0x7fffu + ((x >> 16) & 1u);
  return (us)(r >> 16);
}
static __device__ __forceinline__ void gld16(const void* g, void* l){
  __builtin_amdgcn_global_load_lds(
      (const __attribute__((address_space(1))) unsigned int*)g,
      (__attribute__((address_space(3))) unsigned int*)l, 16, 0, 0);
}

// ---- transpose+cast: [b,256,4096] f32 -> [b,4096,256] bf16, both fmaps one launch --
__global__ void k_transpose_cast(const float* __restrict__ f1,
                                 const float* __restrict__ f2,
                                 us* __restrict__ A, us* __restrict__ B0){
  __shared__ float lds[64][65];
  int z = blockIdx.z;           // 0..3 : b = z&1, which = z>>1
  int b = z & 1, which = z >> 1;
  const float* in = which ? f2 : f1;
  us* out = which ? B0 : A;
  float scale = which ? 1.0f : 0.0625f;   // fold 1/sqrt(256) into A
  int c0 = blockIdx.y * 64, m0 = blockIdx.x * 64;
  const float* ib = in + (size_t)b * K_DIM * M_DIM;
  us* ob = out + (size_t)b * M_DIM * K_DIM;
  int t = threadIdx.x, r = t >> 6, j = t & 63;
#pragma unroll
  for (int k = 0; k < 16; k++)
    lds[r + k*4][j] = ib[(size_t)(c0 + r + k*4) * M_DIM + m0 + j];
  __syncthreads();
#pragma unroll
  for (int k = 0; k < 16; k++)
    ob[(size_t)(m0 + r + k*4) * K_DIM + c0 + j] = f2bf(lds[j][r + k*4] * scale);
}

// ---- pools: B1 (2x2), B2 (4x4), B3 (8x8) all directly from B0, one launch ----------
__global__ void k_pool_all(const us* __restrict__ B0, us* __restrict__ B1,
                           us* __restrict__ B2, us* __restrict__ B3){
  int bid = blockIdx.x;
  us* dst; int wd, f;
  if (bid < 512)      { dst = B1; wd = 32; f = 2; }
  else if (bid < 640) { bid -= 512; dst = B2; wd = 16; f = 4; }
  else                { bid -= 640; dst = B3; wd = 8;  f = 8; }
  int t = threadIdx.x;
  int idx = bid * 4 + (t >> 6);
  int l = t & 63;
  int per = wd * wd;
  int b = idx / per, rem = idx - b * per;
  int y = rem / wd, x = rem - y * wd;
  const us* sb = B0 + (size_t)b * 4096 * K_DIM;
  float s0 = 0, s1 = 0, s2 = 0, s3 = 0;
  for (int dy = 0; dy < f; dy++)
    for (int dx = 0; dx < f; dx++){
      size_t off = ((size_t)(f*y + dy) * 64 + (f*x + dx)) * K_DIM + l * 4;
      uint2 v = *(const uint2*)(sb + off);
      s0 += bf2f(v.x & 0xffff); s1 += bf2f(v.x >> 16);
      s2 += bf2f(v.y & 0xffff); s3 += bf2f(v.y >> 16);
    }
  float inv = 1.0f / (float)(f * f);
  uint2 o;
  o.x = (unsigned)f2bf(s0*inv) | ((unsigned)f2bf(s1*inv) << 16);
  o.y = (unsigned)f2bf(s2*inv) | ((unsigned)f2bf(s3*inv) << 16);
  us* db = dst + (size_t)b * per * K_DIM;
  *(uint2*)(db + (size_t)rem * K_DIM + l * 4) = o;
}

// ---- all 4 GEMMs in one launch; 128x128 tile, BK=32, simple 2-barrier loop ---------
__global__ __launch_bounds__(256) void k_gemm_all(
    const us* __restrict__ A,
    const us* __restrict__ B0, const us* __restrict__ B1,
    const us* __restrict__ B2, const us* __restrict__ B3,
    us* __restrict__ C0, us* __restrict__ C1,
    us* __restrict__ C2, us* __restrict__ C3){
  __shared__ __align__(16) us As[4096];
  __shared__ __align__(16) us Bs[4096];
  int bx = blockIdx.x;
  const us* B; us* C; int N, n0;
  if (bx < 32)      { B = B0; C = C0; N = 4096; n0 = bx * 128; }
  else if (bx < 40) { B = B1; C = C1; N = 1024; n0 = (bx - 32) * 128; }
  else if (bx < 42) { B = B2; C = C2; N = 256;  n0 = (bx - 40) * 128; }
  else              { B = B3; C = C3; N = 64;   n0 = 0; }
  int b = blockIdx.z;
  const us* Ab = A + (size_t)b * M_DIM * K_DIM;
  const us* Bb = B + (size_t)b * N * K_DIM;
  us* Cb = C + (size_t)b * M_DIM * N;
  int m0 = blockIdx.y * 128;
  int t = threadIdx.x;
  int wave = t >> 6, lane = t & 63;
  int wm = (wave >> 1) * 64, wn = (wave & 1) * 64;
  int srow = t >> 2, scol = (t & 3) * 8;
  int fr = lane & 15, fk = (lane >> 4) * 8;
  f32x4 acc[4][4];
#pragma unroll
  for (int i = 0; i < 4; i++)
#pragma unroll
    for (int j = 0; j < 4; j++) acc[i][j] = (f32x4){0.f, 0.f, 0.f, 0.f};

  int nr0 = n0 + srow;      if (nr0 > N - 1) nr0 = N - 1;
  int nr1 = n0 + srow + 64; if (nr1 > N - 1) nr1 = N - 1;
  const us* ga0 = Ab + (size_t)(m0 + srow) * K_DIM + scol;
  const us* ga1 = Ab + (size_t)(m0 + srow + 64) * K_DIM + scol;
  const us* gb0 = Bb + (size_t)nr0 * K_DIM + scol;
  const us* gb1 = Bb + (size_t)nr1 * K_DIM + scol;

  for (int kt = 0; kt < K_DIM; kt += 32){
    __syncthreads();
    gld16(ga0 + kt, As + t * 8);
    gld16(ga1 + kt, As + t * 8 + 2048);
    gld16(gb0 + kt, Bs + t * 8);
    gld16(gb1 + kt, Bs + t * 8 + 2048);
    asm volatile("s_waitcnt vmcnt(0)" ::: "memory");
    __syncthreads();
    bf16x8 af[4], bfv[4];
#pragma unroll
    for (int i = 0; i < 4; i++)
      af[i] = *(const bf16x8*)(As + (wm + i*16 + fr) * 32 + fk);
#pragma unroll
    for (int j = 0; j < 4; j++)
      bfv[j] = *(const bf16x8*)(Bs + (wn + j*16 + fr) * 32 + fk);
#pragma unroll
    for (int i = 0; i < 4; i++)
#pragma unroll
      for (int j = 0; j < 4; j++)
        acc[i][j] = __builtin_amdgcn_mfma_f32_16x16x32_bf16(af[i], bfv[j], acc[i][j], 0, 0, 0);
  }

  int cr = (lane >> 4) * 4, ccol = lane & 15;
#pragma unroll
  for (int i = 0; i < 4; i++){
#pragma unroll
    for (int j = 0; j < 4; j++){
      int col = n0 + wn + j*16 + ccol;
      if (col < N){
        size_t base = (size_t)(m0 + wm + i*16 + cr) * N + col;
#pragma unroll
        for (int r = 0; r < 4; r++)
          Cb[base + (size_t)r * N] = f2bf(acc[i][j][r]);
      }
    }
  }
}

// ---- sampler: one WAVE gathers one (pixel,level) window -> coalesced everything ----
// Block = 4 waves, handles one (i-row, b, lvl): 64 pixels in 16 rounds.
// Gather: 60 lanes = 10 rows x 6 dwords (same-line lanes coalesce).
// Combine: 81 outputs in 2 lane-passes from per-wave LDS W[10][12].
// Store: block-wide coalesced phase via padded S[81][65] staging.
__global__ __launch_bounds__(256) void k_sample(
    const us* __restrict__ p0, const us* __restrict__ p1,
    const us* __restrict__ p2, const us* __restrict__ p3,
    const float* __restrict__ cc, float* __restrict__ out){
  __shared__ float Wt[4][10][12];
  __shared__ float St[81][65];
  int i = blockIdx.x, b = blockIdx.y, lvl = blockIdx.z;
  int t = threadIdx.x, wv = t >> 6, lane = t & 63;
  const us* corr; int wl;
  if (lvl == 0)      { corr = p0; wl = 64; }
  else if (lvl == 1) { corr = p1; wl = 32; }
  else if (lvl == 2) { corr = p2; wl = 16; }
  else               { corr = p3; wl = 8;  }
  float inv = 1.0f / (float)(1 << lvl);
  int v = lane / 6, k = lane - v * 6;   // gather coords (lane<60)

  for (int rnd = 0; rnd < 16; rnd++){
    int jj = rnd * 4 + wv;
    int m = i * 64 + jj;
    const us* rowp = corr + (size_t)(b * M_DIM + m) * (wl * wl);
    float cx = cc[((size_t)(b*2 + 0) * 64 + i) * 64 + jj];
    float cy = cc[((size_t)(b*2 + 1) * 64 + i) * 64 + jj];
    float xs = cx * inv, ys = cy * inv;
    float x0f = floorf(xs), y0f = floorf(ys);
    int bx0 = (int)x0f - 4, by0 = (int)y0f - 4;
    float fx = xs - x0f, fy = ys - y0f;
    int e0 = bx0 & ~1, par = bx0 & 1;

    if (lane < 60){
      int ry = by0 + v;
      bool rok = (unsigned)ry < (unsigned)wl;
      int ryc = ry < 0 ? 0 : (ry > wl - 1 ? wl - 1 : ry);
      int si = e0 + 2 * k;
      int ec = si < 0 ? 0 : (si > wl - 2 ? wl - 2 : si);
      unsigned dv = *(const unsigned*)(rowp + ryc * wl + ec);
      float lo = (rok && (unsigned)si       < (unsigned)wl) ? bf2f(dv & 0xffff) : 0.0f;
      float hi = (rok && (unsigned)(si + 1) < (unsigned)wl) ? bf2f(dv >> 16)    : 0.0f;
      Wt[wv][v][2*k]     = lo;
      Wt[wv][v][2*k + 1] = hi;
    }
    // same-wave DS ordering: LDS ops from one wave execute in order; no barrier needed
    float wx1 = fx, wx0 = 1.0f - fx, wy1 = fy, wy0 = 1.0f - fy;
#pragma unroll
    for (int p = 0; p < 2; p++){
      int o = lane + p * 64;
      if (o < 81){
        int a = o / 9, d = o - a * 9;   // feature o = a*9 + d; a=x-offset, d=y-offset
        float t00 = Wt[wv][d][a + par];
        float t01 = Wt[wv][d][a + par + 1];
        float t10 = Wt[wv][d + 1][a + par];
        float t11 = Wt[wv][d + 1][a + par + 1];
        St[o][jj] = wy0 * (wx0 * t00 + wx1 * t01) + wy1 * (wx0 * t10 + wx1 * t11);
      }
    }
  }

  __syncthreads();
  size_t ob = ((size_t)b * 324 + lvl * 81) * 4096 + (size_t)i * 64;
  int oo = t >> 6, j = t & 63;
#pragma unroll
  for (int r = 0; r < 21; r++){
    int o = oo + r * 4;
    if (o < 81)
      out[ob + (size_t)o * 4096 + j] = St[o][j];
  }
}

extern "C" void kernel_launch(void* const* d_in, const int* in_sizes, int n_in,
                              void* d_out, int out_size, void* d_ws, size_t ws_size,
                              hipStream_t stream){
  (void)in_sizes; (void)n_in; (void)out_size; (void)ws_size;
  const float* f1 = (const float*)d_in[0];
  const float* f2 = (const float*)d_in[1];
  const float* cc = (const float*)d_in[2];
  float* out = (float*)d_out;
  char* ws = (char*)d_ws;
  us* A  = (us*)(ws + 0);          //  4 MB  f1^T bf16 (scaled 1/16)
  us* B0 = (us*)(ws + 4194304);    //  4 MB  f2^T bf16
  us* B1 = (us*)(ws + 8388608);    //  1 MB
  us* B2 = (us*)(ws + 9437184);    //  256 KB
  us* B3 = (us*)(ws + 9699328);    //  64 KB
  us* C0 = (us*)(ws + 9764864);    //  64 MB corr level 0
  us* C1 = (us*)(ws + 76873728);   //  16 MB
  us* C2 = (us*)(ws + 93650944);   //  4 MB
  us* C3 = (us*)(ws + 97845248);   //  1 MB

  k_transpose_cast<<<dim3(64, 4, 4), dim3(256), 0, stream>>>(f1, f2, A, B0);
  k_pool_all<<<dim3(672), dim3(256), 0, stream>>>(B0, B1, B2, B3);
  k_gemm_all<<<dim3(43, 32, 2), dim3(256), 0, stream>>>(A, B0, B1, B2, B3, C0, C1, C2, C3);
  k_sample<<<dim3(64, 2, 4), dim3(256), 0, stream>>>(C0, C1, C2, C3, cc, out);
}